// Round 8
// baseline (282.744 us; speedup 1.0000x reference)
//
#include <hip/hip_runtime.h>
#include <hip/hip_bf16.h>

// CrossWindowAttention3D — round 11: vectorize proj staging.
// proj was top (84us) at 22% HBM, MfmaUtil 2.7, VALUBusy 19 -> latency-bound
// on 48 scalar dword loads/thread in X staging. Rewrite: each thread stages
// 4 voxels x 4 channels via float4-over-vox loads (12 VMEM + 12 b64 LDS
// writes/thread). Shift makes the load 4B-aligned (aligned(4) float4); the
// single wrapping group (w0==44) takes a scalar fallback. W staging float4.
// attn / out_proj / eb unchanged from round 10.
// ws: qw|kw|vw|aw (4 x 21.25 MB bf16) + EB (6.4 MB f32)

#define CH    96
#define DS    48
#define NVOX  (48*48*48)   // 110592
#define WSZ   6
#define NWIN  512
#define NTOK  216
#define NTOKP 224
#define NHEADS 4
#define HD    24
#define XSTR  100          // LDS row stride (shorts) for f16 GEMM tiles
#define VSTR  228          // Vt row stride (shorts)
#define PGRID (NVOX / 128) // 864 blocks per projection
#define CEXP  8.0f

typedef __attribute__((ext_vector_type(4))) float  f32x4;
typedef __attribute__((ext_vector_type(4), aligned(4))) float f32x4u;
typedef __attribute__((ext_vector_type(4))) short  s16x4;
typedef __attribute__((ext_vector_type(8))) short  s16x8;
typedef __attribute__((ext_vector_type(8))) _Float16 f16x8;

static __device__ inline short f2b(float f) {
    union { float f; unsigned u; } v; v.f = f;
    unsigned r = v.u + 0x7FFF + ((v.u >> 16) & 1);   // RTNE
    return (short)(r >> 16);
}
static __device__ inline float bf2f(short s) {
    union { unsigned u; float f; } v;
    v.u = ((unsigned)(unsigned short)s) << 16;
    return v.f;
}
static __device__ inline unsigned pack_f16(float a, float b) {
    unsigned short ua = __builtin_bit_cast(unsigned short, (_Float16)a);
    unsigned short ub = __builtin_bit_cast(unsigned short, (_Float16)b);
    return (unsigned)ua | ((unsigned)ub << 16);
}

// ---- Kernel 0: EB[head][type][224][224] = mask? 0 : exp(bias - CEXP) ----
__global__ __launch_bounds__(256) void eb_kernel(
    const float* __restrict__ rel_table, float* __restrict__ EB)
{
    int idx = blockIdx.x * 256 + threadIdx.x;     // 4*8*224*224, exact grid
    int head = idx / (8 * NTOKP * NTOKP);
    int rem = idx - head * 8 * NTOKP * NTOKP;
    int ty = rem / (NTOKP * NTOKP);
    int rem2 = rem - ty * NTOKP * NTOKP;
    int i = rem2 / NTOKP;
    int j = rem2 - (rem2 / NTOKP) * NTOKP;
    float val = 0.f;
    if (i < NTOK && j < NTOK) {
        int tdi = i / 36, thi = (i / 6) % 6, twi = i % 6;
        int tdj = j / 36, thj = (j / 6) % 6, twj = j % 6;
        bool m = ((ty & 1) && ((tdi < 3) != (tdj < 3))) ||
                 ((ty & 2) && ((thi < 3) != (thj < 3))) ||
                 ((ty & 4) && ((twi < 3) != (twj < 3)));
        int ridx = ((tdi - tdj + 5) * 11 + (thi - thj + 5)) * 11 + (twi - twj + 5);
        float b = rel_table[ridx * NHEADS + head];
        val = m ? 0.f : __expf(b - CEXP);
    }
    EB[idx] = val;
}

// ---- Kernel 1: conv1x1 + shift + window partition via f16 MFMA ----
__global__ __launch_bounds__(256) void proj_mfma_kernel(
    const float* __restrict__ x0, const float* __restrict__ x1, const float* __restrict__ x2,
    const float* __restrict__ W0, const float* __restrict__ W1, const float* __restrict__ W2,
    const float* __restrict__ b0, const float* __restrict__ b1, const float* __restrict__ b2,
    const int* __restrict__ use_shift,
    short* __restrict__ d0, short* __restrict__ d1, short* __restrict__ d2,
    float scale0)
{
    __shared__ short Xs[128 * XSTR];   // f16 [vox][k]; later bf16 [vox][oc]
    __shared__ short Wb[CH * XSTR];    // f16 [oc][k]

    int tid = threadIdx.x;
    int which = blockIdx.x / PGRID;
    int bx = blockIdx.x - which * PGRID;
    int v0 = bx * 128;

    const float* x    = (which == 0) ? x0 : ((which == 1) ? x1 : x2);
    const float* W    = (which == 0) ? W0 : ((which == 1) ? W1 : W2);
    const float* bias = (which == 0) ? b0 : ((which == 1) ? b1 : b2);
    short*       dst  = (which == 0) ? d0 : ((which == 1) ? d1 : d2);
    float scale = (which == 0) ? scale0 : 1.0f;

    // stage W -> f16 LDS: 9 float4 loads/thread
    for (int e = tid; e < CH * 24; e += 256) {
        int oc = e / 24, kq = e - oc * 24;
        f32x4u wv = *(const f32x4u*)&W[oc * CH + 4 * kq];
        unsigned lo = pack_f16(wv[0], wv[1]);
        unsigned hi = pack_f16(wv[2], wv[3]);
        *(uint2*)&Wb[oc * XSTR + 4 * kq] = make_uint2(lo, hi);
    }
    // stage X -> f16 LDS: units of (4 channels x 4 voxels), float4 over vox.
    {
        int s = (use_shift[0] != 0) ? 3 : 0;
        for (int e = tid; e < 768; e += 256) {       // 24 ch4 x 32 grp
            int grp = e & 31;
            int ch4 = e >> 5;                        // 0..23
            int v = v0 + grp * 4;
            int d = v / (DS * DS);
            int rem = v - d * DS * DS;
            int h = rem / DS;
            int w0 = rem - h * DS;                   // multiple of 4, <= 44
            int sd = d + s; if (sd >= DS) sd -= DS;
            int sh = h + s; if (sh >= DS) sh -= DS;
            int w0s = w0 + s;                        // <= 47
            int base = (sd * DS + sh) * DS;
            f32x4u f[4];
            if (w0s <= 44) {                         // contiguous source span
#pragma unroll
                for (int q = 0; q < 4; q++)
                    f[q] = *(const f32x4u*)&x[(ch4 * 4 + q) * NVOX + base + w0s];
            } else {                                 // w0s==47: wraps to 47,0,1,2
#pragma unroll
                for (int q = 0; q < 4; q++) {
                    const float* xc = &x[(ch4 * 4 + q) * NVOX + base];
                    f[q][0] = xc[47]; f[q][1] = xc[0]; f[q][2] = xc[1]; f[q][3] = xc[2];
                }
            }
#pragma unroll
            for (int i = 0; i < 4; i++) {
                unsigned lo = pack_f16(f[0][i], f[1][i]);
                unsigned hi = pack_f16(f[2][i], f[3][i]);
                *(uint2*)&Xs[(grp * 4 + i) * XSTR + ch4 * 4] = make_uint2(lo, hi);
            }
        }
    }
    __syncthreads();

    const int wid = tid >> 6;
    const int lane = tid & 63;
    const int g = lane >> 4;
    const int c = lane & 15;
    const int mrow = wid * 32;

    const f32x4 zero4 = {0.f, 0.f, 0.f, 0.f};
    f32x4 acc[2][6];
#pragma unroll
    for (int i = 0; i < 2; i++)
#pragma unroll
        for (int j = 0; j < 6; j++) acc[i][j] = zero4;

#pragma unroll
    for (int kt = 0; kt < 3; kt++) {
        const short* pa0 = &Xs[(mrow + c) * XSTR + kt * 32 + g * 8];
        s16x4 a0l = *(const s16x4*)pa0;
        s16x4 a0h = *(const s16x4*)(pa0 + 4);
        f16x8 a0 = __builtin_bit_cast(f16x8,
            __builtin_shufflevector(a0l, a0h, 0, 1, 2, 3, 4, 5, 6, 7));
        const short* pa1 = &Xs[(mrow + 16 + c) * XSTR + kt * 32 + g * 8];
        s16x4 a1l = *(const s16x4*)pa1;
        s16x4 a1h = *(const s16x4*)(pa1 + 4);
        f16x8 a1 = __builtin_bit_cast(f16x8,
            __builtin_shufflevector(a1l, a1h, 0, 1, 2, 3, 4, 5, 6, 7));
#pragma unroll
        for (int nt = 0; nt < 6; nt++) {
            const short* pb = &Wb[(nt * 16 + c) * XSTR + kt * 32 + g * 8];
            s16x4 bl = *(const s16x4*)pb;
            s16x4 bh = *(const s16x4*)(pb + 4);
            f16x8 bb = __builtin_bit_cast(f16x8,
                __builtin_shufflevector(bl, bh, 0, 1, 2, 3, 4, 5, 6, 7));
            acc[0][nt] = __builtin_amdgcn_mfma_f32_16x16x32_f16(a0, bb, acc[0][nt], 0, 0, 0);
            acc[1][nt] = __builtin_amdgcn_mfma_f32_16x16x32_f16(a1, bb, acc[1][nt], 0, 0, 0);
        }
    }

    float bs[6];
#pragma unroll
    for (int nt = 0; nt < 6; nt++) bs[nt] = bias[nt * 16 + c];

    __syncthreads();

#pragma unroll
    for (int mtile = 0; mtile < 2; mtile++)
#pragma unroll
        for (int nt = 0; nt < 6; nt++)
#pragma unroll
            for (int r = 0; r < 4; r++) {
                int vox = mrow + mtile * 16 + g * 4 + r;
                int oc = nt * 16 + c;
                Xs[vox * XSTR + oc] = f2b((acc[mtile][nt][r] + bs[nt]) * scale);
            }
    __syncthreads();

    for (int e = tid; e < 512; e += 256) {
        int vox = e >> 2, q = e & 3;
        int v = v0 + vox;
        int d = v / (DS * DS);
        int rem = v - d * DS * DS;
        int h = rem / DS;
        int w = rem - h * DS;
        int widx = (d / WSZ) * 64 + (h / WSZ) * 8 + (w / WSZ);
        int tok  = (d % WSZ) * 36 + (h % WSZ) * WSZ + (w % WSZ);
        short* dp = dst + ((size_t)(widx * NHEADS + q) * NTOK + tok) * HD;
        const short* sp = &Xs[vox * XSTR + q * 24];
        s16x4 a0 = *(const s16x4*)(sp);
        s16x4 a1 = *(const s16x4*)(sp + 4);
        s16x4 a2 = *(const s16x4*)(sp + 8);
        s16x4 a3 = *(const s16x4*)(sp + 12);
        s16x4 a4 = *(const s16x4*)(sp + 16);
        s16x4 a5 = *(const s16x4*)(sp + 20);
        *(s16x8*)(dp)      = __builtin_shufflevector(a0, a1, 0, 1, 2, 3, 4, 5, 6, 7);
        *(s16x8*)(dp + 8)  = __builtin_shufflevector(a2, a3, 0, 1, 2, 3, 4, 5, 6, 7);
        *(s16x8*)(dp + 16) = __builtin_shufflevector(a4, a5, 0, 1, 2, 3, 4, 5, 6, 7);
    }
}

// ---- Kernel 2: MFMA windowed attention (unchanged from round 10) ----
__global__ __launch_bounds__(256) void attn_mfma_kernel(
    const short* __restrict__ qw, const short* __restrict__ kw,
    const short* __restrict__ vw, const float* __restrict__ EB,
    const int* __restrict__ use_shift, short* __restrict__ aw)
{
    __shared__ short Ks[NTOK * 36];
    __shared__ short Vt[32 * VSTR];
    __shared__ short PO[4][576];

    int widx = blockIdx.x >> 2;
    int head = blockIdx.x & 3;
    int tid = threadIdx.x;
    bool shift = (use_shift[0] != 0);
    int wd = widx >> 6, wh = (widx >> 3) & 7, ww = widx & 7;
    int ty = shift ? ((wd == 7 ? 1 : 0) | (wh == 7 ? 2 : 0) | (ww == 7 ? 4 : 0)) : 0;

    {
        int* z2 = (int*)Ks; int* z3 = (int*)Vt;
        for (int i = tid; i < NTOK * 18; i += 256) z2[i] = 0;
        for (int i = tid; i < 16 * VSTR; i += 256)
            z3[i] = (i >= 12 * VSTR && i < (25 * VSTR) / 2) ? 0x3F803F80 : 0;
    }
    __syncthreads();

    const size_t hbase = (size_t)(widx * NHEADS + head) * NTOK * HD;

    for (int e = tid; e < NTOK * 3; e += 256) {
        int t = e / 3, ch = e - t * 3;
        const short* kp = kw + hbase + t * 24 + ch * 8;
        s16x8 k8 = *(const s16x8*)kp;
        *(s16x4*)&Ks[t * 36 + ch * 8]     = __builtin_shufflevector(k8, k8, 0, 1, 2, 3);
        *(s16x4*)&Ks[t * 36 + ch * 8 + 4] = __builtin_shufflevector(k8, k8, 4, 5, 6, 7);
        s16x8 v8 = *(const s16x8*)(vw + hbase + t * 24 + ch * 8);
#pragma unroll
        for (int j = 0; j < 8; j++) Vt[(ch * 8 + j) * VSTR + t] = v8[j];
    }
    __syncthreads();

    const int wid = tid >> 6;
    const int lane = tid & 63;
    const int g = lane >> 4;
    const int c = lane & 15;

    const f32x4 zero4 = {0.f, 0.f, 0.f, 0.f};
    short* myPs = &PO[wid][0];
    const float* EBt = EB + (size_t)(head * 8 + ty) * NTOKP * NTOKP;

    for (int mt = wid; mt < 14; mt += 4) {
        int m0 = mt * 16;
        s16x8 aq = {0, 0, 0, 0, 0, 0, 0, 0};
        int qtok = m0 + c;
        if (g < 3 && qtok < NTOK)
            aq = *(const s16x8*)(qw + hbase + (size_t)qtok * HD + g * 8);
        f32x4 sreg[14];
#pragma unroll
        for (int t = 0; t < 14; t++) {
            int krow = (t < 13) ? (t * 16 + c) : (208 + (c & 7));
            const short* p = &Ks[krow * 36 + g * 8];
            s16x4 lo = *(const s16x4*)p;
            s16x4 hi = *(const s16x4*)(p + 4);
            s16x8 bk = __builtin_shufflevector(lo, hi, 0, 1, 2, 3, 4, 5, 6, 7);
            sreg[t] = __builtin_amdgcn_mfma_f32_16x16x32_bf16(aq, bk, zero4, 0, 0, 0);
        }
        const float* ebr[4];
#pragma unroll
        for (int r = 0; r < 4; r++)
            ebr[r] = EBt + (size_t)(m0 + g * 4 + r) * NTOKP + c;
#pragma unroll
        for (int t = 0; t < 14; t++)
#pragma unroll
            for (int r = 0; r < 4; r++)
                sreg[t][r] = __expf(sreg[t][r]) * ebr[r][t * 16];

        f32x4 o0 = zero4, o1 = zero4;
#pragma unroll
        for (int kt = 0; kt < 7; kt++) {
#pragma unroll
            for (int tt = 0; tt < 2; tt++) {
                int t = kt * 2 + tt;
#pragma unroll
                for (int r = 0; r < 4; r++)
                    myPs[(g * 4 + r) * 36 + tt * 16 + c] = f2b(sreg[t][r]);
            }
            const short* p = &myPs[c * 36 + g * 8];
            s16x4 lo = *(const s16x4*)p;
            s16x4 hi = *(const s16x4*)(p + 4);
            s16x8 ap = __builtin_shufflevector(lo, hi, 0, 1, 2, 3, 4, 5, 6, 7);
            const short* pv0 = &Vt[c * VSTR + kt * 32 + g * 8];
            s16x4 v0l = *(const s16x4*)pv0;
            s16x4 v0h = *(const s16x4*)(pv0 + 4);
            s16x8 bv0 = __builtin_shufflevector(v0l, v0h, 0, 1, 2, 3, 4, 5, 6, 7);
            const short* pv1 = &Vt[(16 + c) * VSTR + kt * 32 + g * 8];
            s16x4 v1l = *(const s16x4*)pv1;
            s16x4 v1h = *(const s16x4*)(pv1 + 4);
            s16x8 bv1 = __builtin_shufflevector(v1l, v1h, 0, 1, 2, 3, 4, 5, 6, 7);
            o0 = __builtin_amdgcn_mfma_f32_16x16x32_bf16(ap, bv0, o0, 0, 0, 0);
            o1 = __builtin_amdgcn_mfma_f32_16x16x32_bf16(ap, bv1, o1, 0, 0, 0);
        }

#pragma unroll
        for (int r = 0; r < 4; r++) {
            float sm = __shfl(o1[r], (lane & 48) + 8);
            float ri = 1.f / sm;
            int row = g * 4 + r;
            myPs[row * 24 + c] = f2b(o0[r] * ri);
            if (c < 8) myPs[row * 24 + 16 + c] = f2b(o1[r] * ri);
        }
        int nrow = NTOK - m0; if (nrow > 16) nrow = 16;
        int nsh = nrow * 24;
        short* dstw = aw + hbase + (size_t)m0 * HD;
        for (int j = lane; j * 8 < nsh; j += 64)
            *(s16x8*)(dstw + j * 8) = *(const s16x8*)(myPs + j * 8);
    }
}

// ---- Kernel 3: output projection via f16 MFMA, swapped operands ----
__global__ __launch_bounds__(256) void out_proj_mfma_kernel(
    const short* __restrict__ aw, const float* __restrict__ Wp,
    const float* __restrict__ bp, const int* __restrict__ use_shift,
    float* __restrict__ out)
{
    __shared__ short Xs[128 * XSTR];   // f16 [vox][ch]
    __shared__ short Wb[CH * XSTR];    // f16 [oc][ic]

    int tid = threadIdx.x;
    int v0 = blockIdx.x * 128;

    for (int e = tid; e < CH * 24; e += 256) {
        int oc = e / 24, kq = e - oc * 24;
        f32x4u wv = *(const f32x4u*)&Wp[oc * CH + 4 * kq];
        unsigned lo = pack_f16(wv[0], wv[1]);
        unsigned hi = pack_f16(wv[2], wv[3]);
        *(uint2*)&Wb[oc * XSTR + 4 * kq] = make_uint2(lo, hi);
    }
    for (int e = tid; e < 512; e += 256) {
        int vox = e >> 2, hq = e & 3;
        int v = v0 + vox;
        int d = v / (DS * DS);
        int rem = v - d * DS * DS;
        int h = rem / DS;
        int w = rem - h * DS;
        int s = (use_shift[0] != 0) ? 3 : 0;
        int sd = d - s; if (sd < 0) sd += DS;
        int s_h = h - s; if (s_h < 0) s_h += DS;
        int s_w = w - s; if (s_w < 0) s_w += DS;
        int widx = (sd / WSZ) * 64 + (s_h / WSZ) * 8 + (s_w / WSZ);
        int tok  = (sd % WSZ) * 36 + (s_h % WSZ) * WSZ + (s_w % WSZ);
        const short* sp = aw + ((size_t)(widx * NHEADS + hq) * NTOK + tok) * HD;
#pragma unroll
        for (int j3 = 0; j3 < 3; j3++) {
            s16x8 a = *(const s16x8*)(sp + 8 * j3);
#pragma unroll
            for (int p = 0; p < 4; p++)
                *(unsigned*)&Xs[vox * XSTR + hq * 24 + 8 * j3 + 2 * p] =
                    pack_f16(bf2f(a[2 * p]), bf2f(a[2 * p + 1]));
        }
    }
    __syncthreads();

    const int wid = tid >> 6;
    const int lane = tid & 63;
    const int g = lane >> 4;
    const int c = lane & 15;

    const f32x4 zero4 = {0.f, 0.f, 0.f, 0.f};
    f32x4 acc[2][6];
#pragma unroll
    for (int i = 0; i < 2; i++)
#pragma unroll
        for (int j = 0; j < 6; j++) acc[i][j] = zero4;

#pragma unroll
    for (int kt = 0; kt < 3; kt++) {
        f16x8 bfr[2];
#pragma unroll
        for (int mi = 0; mi < 2; mi++) {
            const short* pb = &Xs[((2 * wid + mi) * 16 + c) * XSTR + kt * 32 + g * 8];
            s16x4 bl = *(const s16x4*)pb;
            s16x4 bh = *(const s16x4*)(pb + 4);
            bfr[mi] = __builtin_bit_cast(f16x8,
                __builtin_shufflevector(bl, bh, 0, 1, 2, 3, 4, 5, 6, 7));
        }
#pragma unroll
        for (int nt = 0; nt < 6; nt++) {
            const short* pa = &Wb[(nt * 16 + c) * XSTR + kt * 32 + g * 8];
            s16x4 al = *(const s16x4*)pa;
            s16x4 ah = *(const s16x4*)(pa + 4);
            f16x8 af = __builtin_bit_cast(f16x8,
                __builtin_shufflevector(al, ah, 0, 1, 2, 3, 4, 5, 6, 7));
            acc[0][nt] = __builtin_amdgcn_mfma_f32_16x16x32_f16(af, bfr[0], acc[0][nt], 0, 0, 0);
            acc[1][nt] = __builtin_amdgcn_mfma_f32_16x16x32_f16(af, bfr[1], acc[1][nt], 0, 0, 0);
        }
    }

#pragma unroll
    for (int nt = 0; nt < 6; nt++)
#pragma unroll
        for (int r = 0; r < 4; r++) {
            int oc = nt * 16 + g * 4 + r;
            float bb = bp[oc];
#pragma unroll
            for (int mi = 0; mi < 2; mi++) {
                int vox = v0 + (2 * wid + mi) * 16 + c;
                out[(size_t)oc * NVOX + vox] = acc[mi][nt][r] + bb;
            }
        }
}

extern "C" void kernel_launch(void* const* d_in, const int* in_sizes, int n_in,
                              void* d_out, int out_size, void* d_ws, size_t ws_size,
                              hipStream_t stream)
{
    const float* q_in = (const float*)d_in[0];
    const float* k_in = (const float*)d_in[1];
    const float* v_in = (const float*)d_in[2];
    const float* Wq   = (const float*)d_in[3];
    const float* bq   = (const float*)d_in[4];
    const float* Wk   = (const float*)d_in[5];
    const float* bk   = (const float*)d_in[6];
    const float* Wv   = (const float*)d_in[7];
    const float* bv   = (const float*)d_in[8];
    const float* Wp   = (const float*)d_in[9];
    const float* bp   = (const float*)d_in[10];
    const float* rel_table = (const float*)d_in[11];
    const int*   use_shift = (const int*)d_in[12];

    const size_t NELEM = (size_t)NWIN * NTOK * CH;   // 10,616,832
    short* qw = (short*)d_ws;                        // bf16
    short* kw = qw + NELEM;
    short* vw = kw + NELEM;
    short* aw = vw + NELEM;                          // bf16
    float* EB = (float*)(aw + NELEM);                // 4*8*224*224 f32, 6.4MB

    const float scale = 0.20412414523193154f;  // 1/sqrt(24)

    eb_kernel<<<NHEADS * 8 * NTOKP * NTOKP / 256, 256, 0, stream>>>(rel_table, EB);
    proj_mfma_kernel<<<3 * PGRID, 256, 0, stream>>>(
        q_in, k_in, v_in, Wq, Wk, Wv, bq, bk, bv, use_shift, qw, kw, vw, scale);
    attn_mfma_kernel<<<NWIN * NHEADS, 256, 0, stream>>>(qw, kw, vw, EB, use_shift, aw);
    out_proj_mfma_kernel<<<PGRID, 256, 0, stream>>>(aw, Wp, bp, use_shift, (float*)d_out);
}

// Round 9
// 279.445 us; speedup vs baseline: 1.0118x; 1.0118x over previous
//
#include <hip/hip_runtime.h>
#include <hip/hip_bf16.h>

// CrossWindowAttention3D — round 12: occupancy, not instruction count.
// Round-11 lesson: proj is latency-exposure-bound (all pipes idle, 3 blocks/
// CU). Revert X staging to round-10 scalar form (measured faster) and delete
// the 19.2KB Wb LDS tile from proj/out_proj: W pre-converted to f16 once
// (wconv_kernel), B-frags loaded straight from global (16B, L2-hot).
// LDS 45K -> 25.6K => 6 blocks/CU. attn unchanged.
// ws: qw|kw|vw|aw (4 x 21.25 MB bf16) + Wf (144KB f16) + EB (6.4 MB f32)

#define CH    96
#define DS    48
#define NVOX  (48*48*48)   // 110592
#define WSZ   6
#define NWIN  512
#define NTOK  216
#define NTOKP 224
#define NHEADS 4
#define HD    24
#define XSTR  100          // LDS row stride (shorts) for f16 GEMM tiles
#define VSTR  228          // Vt row stride (shorts)
#define PGRID (NVOX / 128) // 864 blocks per projection
#define CEXP  8.0f

typedef __attribute__((ext_vector_type(4))) float  f32x4;
typedef __attribute__((ext_vector_type(4))) short  s16x4;
typedef __attribute__((ext_vector_type(8))) short  s16x8;
typedef __attribute__((ext_vector_type(8))) _Float16 f16x8;

static __device__ inline short f2b(float f) {
    union { float f; unsigned u; } v; v.f = f;
    unsigned r = v.u + 0x7FFF + ((v.u >> 16) & 1);   // RTNE
    return (short)(r >> 16);
}
static __device__ inline float bf2f(short s) {
    union { unsigned u; float f; } v;
    v.u = ((unsigned)(unsigned short)s) << 16;
    return v.f;
}
static __device__ inline unsigned pack_f16(float a, float b) {
    unsigned short ua = __builtin_bit_cast(unsigned short, (_Float16)a);
    unsigned short ub = __builtin_bit_cast(unsigned short, (_Float16)b);
    return (unsigned)ua | ((unsigned)ub << 16);
}

// ---- Kernel -1: convert the 4 weight matrices to f16 (dense [oc][96]) ----
__global__ __launch_bounds__(256) void wconv_kernel(
    const float* __restrict__ W0, const float* __restrict__ W1,
    const float* __restrict__ W2, const float* __restrict__ W3,
    short* __restrict__ Wf)
{
    int idx = blockIdx.x * 256 + threadIdx.x;   // grid 144 -> 36864, exact
    int m = idx / 9216;
    int r = idx - m * 9216;
    const float* W = (m == 0) ? W0 : ((m == 1) ? W1 : ((m == 2) ? W2 : W3));
    Wf[idx] = __builtin_bit_cast(short, (_Float16)W[r]);
}

// ---- Kernel 0: EB[head][type][224][224] = mask? 0 : exp(bias - CEXP) ----
__global__ __launch_bounds__(256) void eb_kernel(
    const float* __restrict__ rel_table, float* __restrict__ EB)
{
    int idx = blockIdx.x * 256 + threadIdx.x;     // 4*8*224*224, exact grid
    int head = idx / (8 * NTOKP * NTOKP);
    int rem = idx - head * 8 * NTOKP * NTOKP;
    int ty = rem / (NTOKP * NTOKP);
    int rem2 = rem - ty * NTOKP * NTOKP;
    int i = rem2 / NTOKP;
    int j = rem2 - (rem2 / NTOKP) * NTOKP;
    float val = 0.f;
    if (i < NTOK && j < NTOK) {
        int tdi = i / 36, thi = (i / 6) % 6, twi = i % 6;
        int tdj = j / 36, thj = (j / 6) % 6, twj = j % 6;
        bool m = ((ty & 1) && ((tdi < 3) != (tdj < 3))) ||
                 ((ty & 2) && ((thi < 3) != (thj < 3))) ||
                 ((ty & 4) && ((twi < 3) != (twj < 3)));
        int ridx = ((tdi - tdj + 5) * 11 + (thi - thj + 5)) * 11 + (twi - twj + 5);
        float b = rel_table[ridx * NHEADS + head];
        val = m ? 0.f : __expf(b - CEXP);
    }
    EB[idx] = val;
}

// ---- Kernel 1: conv1x1 + shift + window partition via f16 MFMA ----
// LDS: Xs only (25.6KB) -> 6 blocks/CU. B-frags direct from global f16 W.
__global__ __launch_bounds__(256) void proj_mfma_kernel(
    const float* __restrict__ x0, const float* __restrict__ x1, const float* __restrict__ x2,
    const short* __restrict__ Wf,
    const float* __restrict__ b0, const float* __restrict__ b1, const float* __restrict__ b2,
    const int* __restrict__ use_shift,
    short* __restrict__ d0, short* __restrict__ d1, short* __restrict__ d2,
    float scale0)
{
    __shared__ short Xs[128 * XSTR];   // f16 [vox][k]; later bf16 [vox][oc]

    int tid = threadIdx.x;
    int which = blockIdx.x / PGRID;
    int bx = blockIdx.x - which * PGRID;
    int v0 = bx * 128;

    const float* x    = (which == 0) ? x0 : ((which == 1) ? x1 : x2);
    const float* bias = (which == 0) ? b0 : ((which == 1) ? b1 : b2);
    short*       dst  = (which == 0) ? d0 : ((which == 1) ? d1 : d2);
    const short* Wfp  = Wf + which * 9216;
    float scale = (which == 0) ? scale0 : 1.0f;

    // stage X -> f16 LDS (round-10 form: thread owns one voxel, scalar loads)
    {
        int vox = tid & 127;
        int v = v0 + vox;
        int d = v / (DS * DS);
        int rem = v - d * DS * DS;
        int h = rem / DS;
        int w = rem - h * DS;
        int s = (use_shift[0] != 0) ? 3 : 0;
        int sd = d + s; if (sd >= DS) sd -= DS;
        int s_h = h + s; if (s_h >= DS) s_h -= DS;
        int s_w = w + s; if (s_w >= DS) s_w -= DS;
        int src = (sd * DS + s_h) * DS + s_w;
        for (int e = tid; e < 128 * 48; e += 256) {
            int kp = e >> 7;
            float xa = x[(2 * kp) * NVOX + src];
            float xb = x[(2 * kp + 1) * NVOX + src];
            *(unsigned*)&Xs[vox * XSTR + 2 * kp] = pack_f16(xa, xb);
        }
    }
    __syncthreads();

    const int wid = tid >> 6;
    const int lane = tid & 63;
    const int g = lane >> 4;
    const int c = lane & 15;
    const int mrow = wid * 32;

    const f32x4 zero4 = {0.f, 0.f, 0.f, 0.f};
    f32x4 acc[2][6];
#pragma unroll
    for (int i = 0; i < 2; i++)
#pragma unroll
        for (int j = 0; j < 6; j++) acc[i][j] = zero4;

#pragma unroll
    for (int kt = 0; kt < 3; kt++) {
        const short* pa0 = &Xs[(mrow + c) * XSTR + kt * 32 + g * 8];
        s16x4 a0l = *(const s16x4*)pa0;
        s16x4 a0h = *(const s16x4*)(pa0 + 4);
        f16x8 a0 = __builtin_bit_cast(f16x8,
            __builtin_shufflevector(a0l, a0h, 0, 1, 2, 3, 4, 5, 6, 7));
        const short* pa1 = &Xs[(mrow + 16 + c) * XSTR + kt * 32 + g * 8];
        s16x4 a1l = *(const s16x4*)pa1;
        s16x4 a1h = *(const s16x4*)(pa1 + 4);
        f16x8 a1 = __builtin_bit_cast(f16x8,
            __builtin_shufflevector(a1l, a1h, 0, 1, 2, 3, 4, 5, 6, 7));
#pragma unroll
        for (int nt = 0; nt < 6; nt++) {
            f16x8 bb = __builtin_bit_cast(f16x8,
                *(const s16x8*)&Wfp[(nt * 16 + c) * CH + kt * 32 + g * 8]);
            acc[0][nt] = __builtin_amdgcn_mfma_f32_16x16x32_f16(a0, bb, acc[0][nt], 0, 0, 0);
            acc[1][nt] = __builtin_amdgcn_mfma_f32_16x16x32_f16(a1, bb, acc[1][nt], 0, 0, 0);
        }
    }

    float bs[6];
#pragma unroll
    for (int nt = 0; nt < 6; nt++) bs[nt] = bias[nt * 16 + c];

    __syncthreads();

#pragma unroll
    for (int mtile = 0; mtile < 2; mtile++)
#pragma unroll
        for (int nt = 0; nt < 6; nt++)
#pragma unroll
            for (int r = 0; r < 4; r++) {
                int vox = mrow + mtile * 16 + g * 4 + r;
                int oc = nt * 16 + c;
                Xs[vox * XSTR + oc] = f2b((acc[mtile][nt][r] + bs[nt]) * scale);
            }
    __syncthreads();

    for (int e = tid; e < 512; e += 256) {
        int vox = e >> 2, q = e & 3;
        int v = v0 + vox;
        int d = v / (DS * DS);
        int rem = v - d * DS * DS;
        int h = rem / DS;
        int w = rem - h * DS;
        int widx = (d / WSZ) * 64 + (h / WSZ) * 8 + (w / WSZ);
        int tok  = (d % WSZ) * 36 + (h % WSZ) * WSZ + (w % WSZ);
        short* dp = dst + ((size_t)(widx * NHEADS + q) * NTOK + tok) * HD;
        const short* sp = &Xs[vox * XSTR + q * 24];
        s16x4 a0 = *(const s16x4*)(sp);
        s16x4 a1 = *(const s16x4*)(sp + 4);
        s16x4 a2 = *(const s16x4*)(sp + 8);
        s16x4 a3 = *(const s16x4*)(sp + 12);
        s16x4 a4 = *(const s16x4*)(sp + 16);
        s16x4 a5 = *(const s16x4*)(sp + 20);
        *(s16x8*)(dp)      = __builtin_shufflevector(a0, a1, 0, 1, 2, 3, 4, 5, 6, 7);
        *(s16x8*)(dp + 8)  = __builtin_shufflevector(a2, a3, 0, 1, 2, 3, 4, 5, 6, 7);
        *(s16x8*)(dp + 16) = __builtin_shufflevector(a4, a5, 0, 1, 2, 3, 4, 5, 6, 7);
    }
}

// ---- Kernel 2: MFMA windowed attention (unchanged from round 10) ----
__global__ __launch_bounds__(256) void attn_mfma_kernel(
    const short* __restrict__ qw, const short* __restrict__ kw,
    const short* __restrict__ vw, const float* __restrict__ EB,
    const int* __restrict__ use_shift, short* __restrict__ aw)
{
    __shared__ short Ks[NTOK * 36];
    __shared__ short Vt[32 * VSTR];
    __shared__ short PO[4][576];

    int widx = blockIdx.x >> 2;
    int head = blockIdx.x & 3;
    int tid = threadIdx.x;
    bool shift = (use_shift[0] != 0);
    int wd = widx >> 6, wh = (widx >> 3) & 7, ww = widx & 7;
    int ty = shift ? ((wd == 7 ? 1 : 0) | (wh == 7 ? 2 : 0) | (ww == 7 ? 4 : 0)) : 0;

    {
        int* z2 = (int*)Ks; int* z3 = (int*)Vt;
        for (int i = tid; i < NTOK * 18; i += 256) z2[i] = 0;
        for (int i = tid; i < 16 * VSTR; i += 256)
            z3[i] = (i >= 12 * VSTR && i < (25 * VSTR) / 2) ? 0x3F803F80 : 0;
    }
    __syncthreads();

    const size_t hbase = (size_t)(widx * NHEADS + head) * NTOK * HD;

    for (int e = tid; e < NTOK * 3; e += 256) {
        int t = e / 3, ch = e - t * 3;
        const short* kp = kw + hbase + t * 24 + ch * 8;
        s16x8 k8 = *(const s16x8*)kp;
        *(s16x4*)&Ks[t * 36 + ch * 8]     = __builtin_shufflevector(k8, k8, 0, 1, 2, 3);
        *(s16x4*)&Ks[t * 36 + ch * 8 + 4] = __builtin_shufflevector(k8, k8, 4, 5, 6, 7);
        s16x8 v8 = *(const s16x8*)(vw + hbase + t * 24 + ch * 8);
#pragma unroll
        for (int j = 0; j < 8; j++) Vt[(ch * 8 + j) * VSTR + t] = v8[j];
    }
    __syncthreads();

    const int wid = tid >> 6;
    const int lane = tid & 63;
    const int g = lane >> 4;
    const int c = lane & 15;

    const f32x4 zero4 = {0.f, 0.f, 0.f, 0.f};
    short* myPs = &PO[wid][0];
    const float* EBt = EB + (size_t)(head * 8 + ty) * NTOKP * NTOKP;

    for (int mt = wid; mt < 14; mt += 4) {
        int m0 = mt * 16;
        s16x8 aq = {0, 0, 0, 0, 0, 0, 0, 0};
        int qtok = m0 + c;
        if (g < 3 && qtok < NTOK)
            aq = *(const s16x8*)(qw + hbase + (size_t)qtok * HD + g * 8);
        f32x4 sreg[14];
#pragma unroll
        for (int t = 0; t < 14; t++) {
            int krow = (t < 13) ? (t * 16 + c) : (208 + (c & 7));
            const short* p = &Ks[krow * 36 + g * 8];
            s16x4 lo = *(const s16x4*)p;
            s16x4 hi = *(const s16x4*)(p + 4);
            s16x8 bk = __builtin_shufflevector(lo, hi, 0, 1, 2, 3, 4, 5, 6, 7);
            sreg[t] = __builtin_amdgcn_mfma_f32_16x16x32_bf16(aq, bk, zero4, 0, 0, 0);
        }
        const float* ebr[4];
#pragma unroll
        for (int r = 0; r < 4; r++)
            ebr[r] = EBt + (size_t)(m0 + g * 4 + r) * NTOKP + c;
#pragma unroll
        for (int t = 0; t < 14; t++)
#pragma unroll
            for (int r = 0; r < 4; r++)
                sreg[t][r] = __expf(sreg[t][r]) * ebr[r][t * 16];

        f32x4 o0 = zero4, o1 = zero4;
#pragma unroll
        for (int kt = 0; kt < 7; kt++) {
#pragma unroll
            for (int tt = 0; tt < 2; tt++) {
                int t = kt * 2 + tt;
#pragma unroll
                for (int r = 0; r < 4; r++)
                    myPs[(g * 4 + r) * 36 + tt * 16 + c] = f2b(sreg[t][r]);
            }
            const short* p = &myPs[c * 36 + g * 8];
            s16x4 lo = *(const s16x4*)p;
            s16x4 hi = *(const s16x4*)(p + 4);
            s16x8 ap = __builtin_shufflevector(lo, hi, 0, 1, 2, 3, 4, 5, 6, 7);
            const short* pv0 = &Vt[c * VSTR + kt * 32 + g * 8];
            s16x4 v0l = *(const s16x4*)pv0;
            s16x4 v0h = *(const s16x4*)(pv0 + 4);
            s16x8 bv0 = __builtin_shufflevector(v0l, v0h, 0, 1, 2, 3, 4, 5, 6, 7);
            const short* pv1 = &Vt[(16 + c) * VSTR + kt * 32 + g * 8];
            s16x4 v1l = *(const s16x4*)pv1;
            s16x4 v1h = *(const s16x4*)(pv1 + 4);
            s16x8 bv1 = __builtin_shufflevector(v1l, v1h, 0, 1, 2, 3, 4, 5, 6, 7);
            o0 = __builtin_amdgcn_mfma_f32_16x16x32_bf16(ap, bv0, o0, 0, 0, 0);
            o1 = __builtin_amdgcn_mfma_f32_16x16x32_bf16(ap, bv1, o1, 0, 0, 0);
        }

#pragma unroll
        for (int r = 0; r < 4; r++) {
            float sm = __shfl(o1[r], (lane & 48) + 8);
            float ri = 1.f / sm;
            int row = g * 4 + r;
            myPs[row * 24 + c] = f2b(o0[r] * ri);
            if (c < 8) myPs[row * 24 + 16 + c] = f2b(o1[r] * ri);
        }
        int nrow = NTOK - m0; if (nrow > 16) nrow = 16;
        int nsh = nrow * 24;
        short* dstw = aw + hbase + (size_t)m0 * HD;
        for (int j = lane; j * 8 < nsh; j += 64)
            *(s16x8*)(dstw + j * 8) = *(const s16x8*)(myPs + j * 8);
    }
}

// ---- Kernel 3: output projection via f16 MFMA, swapped operands ----
// LDS: Xs only (25.6KB) -> 6 blocks/CU. A-frags direct from global f16 Wp.
__global__ __launch_bounds__(256) void out_proj_mfma_kernel(
    const short* __restrict__ aw, const short* __restrict__ Wfp,
    const float* __restrict__ bp, const int* __restrict__ use_shift,
    float* __restrict__ out)
{
    __shared__ short Xs[128 * XSTR];   // f16 [vox][ch]

    int tid = threadIdx.x;
    int v0 = blockIdx.x * 128;

    for (int e = tid; e < 512; e += 256) {
        int vox = e >> 2, hq = e & 3;
        int v = v0 + vox;
        int d = v / (DS * DS);
        int rem = v - d * DS * DS;
        int h = rem / DS;
        int w = rem - h * DS;
        int s = (use_shift[0] != 0) ? 3 : 0;
        int sd = d - s; if (sd < 0) sd += DS;
        int s_h = h - s; if (s_h < 0) s_h += DS;
        int s_w = w - s; if (s_w < 0) s_w += DS;
        int widx = (sd / WSZ) * 64 + (s_h / WSZ) * 8 + (s_w / WSZ);
        int tok  = (sd % WSZ) * 36 + (s_h % WSZ) * WSZ + (s_w % WSZ);
        const short* sp = aw + ((size_t)(widx * NHEADS + hq) * NTOK + tok) * HD;
#pragma unroll
        for (int j3 = 0; j3 < 3; j3++) {
            s16x8 a = *(const s16x8*)(sp + 8 * j3);
#pragma unroll
            for (int p = 0; p < 4; p++)
                *(unsigned*)&Xs[vox * XSTR + hq * 24 + 8 * j3 + 2 * p] =
                    pack_f16(bf2f(a[2 * p]), bf2f(a[2 * p + 1]));
        }
    }
    __syncthreads();

    const int wid = tid >> 6;
    const int lane = tid & 63;
    const int g = lane >> 4;
    const int c = lane & 15;

    const f32x4 zero4 = {0.f, 0.f, 0.f, 0.f};
    f32x4 acc[2][6];
#pragma unroll
    for (int i = 0; i < 2; i++)
#pragma unroll
        for (int j = 0; j < 6; j++) acc[i][j] = zero4;

#pragma unroll
    for (int kt = 0; kt < 3; kt++) {
        f16x8 bfr[2];
#pragma unroll
        for (int mi = 0; mi < 2; mi++) {
            const short* pb = &Xs[((2 * wid + mi) * 16 + c) * XSTR + kt * 32 + g * 8];
            s16x4 bl = *(const s16x4*)pb;
            s16x4 bh = *(const s16x4*)(pb + 4);
            bfr[mi] = __builtin_bit_cast(f16x8,
                __builtin_shufflevector(bl, bh, 0, 1, 2, 3, 4, 5, 6, 7));
        }
#pragma unroll
        for (int nt = 0; nt < 6; nt++) {
            f16x8 af = __builtin_bit_cast(f16x8,
                *(const s16x8*)&Wfp[(nt * 16 + c) * CH + kt * 32 + g * 8]);
            acc[0][nt] = __builtin_amdgcn_mfma_f32_16x16x32_f16(af, bfr[0], acc[0][nt], 0, 0, 0);
            acc[1][nt] = __builtin_amdgcn_mfma_f32_16x16x32_f16(af, bfr[1], acc[1][nt], 0, 0, 0);
        }
    }

#pragma unroll
    for (int nt = 0; nt < 6; nt++)
#pragma unroll
        for (int r = 0; r < 4; r++) {
            int oc = nt * 16 + g * 4 + r;
            float bb = bp[oc];
#pragma unroll
            for (int mi = 0; mi < 2; mi++) {
                int vox = v0 + (2 * wid + mi) * 16 + c;
                out[(size_t)oc * NVOX + vox] = acc[mi][nt][r] + bb;
            }
        }
}

extern "C" void kernel_launch(void* const* d_in, const int* in_sizes, int n_in,
                              void* d_out, int out_size, void* d_ws, size_t ws_size,
                              hipStream_t stream)
{
    const float* q_in = (const float*)d_in[0];
    const float* k_in = (const float*)d_in[1];
    const float* v_in = (const float*)d_in[2];
    const float* Wq   = (const float*)d_in[3];
    const float* bq   = (const float*)d_in[4];
    const float* Wk   = (const float*)d_in[5];
    const float* bk   = (const float*)d_in[6];
    const float* Wv   = (const float*)d_in[7];
    const float* bv   = (const float*)d_in[8];
    const float* Wp   = (const float*)d_in[9];
    const float* bp   = (const float*)d_in[10];
    const float* rel_table = (const float*)d_in[11];
    const int*   use_shift = (const int*)d_in[12];

    const size_t NELEM = (size_t)NWIN * NTOK * CH;   // 10,616,832
    short* qw = (short*)d_ws;                        // bf16
    short* kw = qw + NELEM;
    short* vw = kw + NELEM;
    short* aw = vw + NELEM;                          // bf16
    short* Wf = aw + NELEM;                          // 4*9216 f16 (Wq,Wk,Wv,Wp)
    float* EB = (float*)(Wf + 4 * 9216);             // 4*8*224*224 f32, 6.4MB

    const float scale = 0.20412414523193154f;  // 1/sqrt(24)

    wconv_kernel<<<144, 256, 0, stream>>>(Wq, Wk, Wv, Wp, Wf);
    eb_kernel<<<NHEADS * 8 * NTOKP * NTOKP / 256, 256, 0, stream>>>(rel_table, EB);
    proj_mfma_kernel<<<3 * PGRID, 256, 0, stream>>>(
        q_in, k_in, v_in, Wf, bq, bk, bv, use_shift, qw, kw, vw, scale);
    attn_mfma_kernel<<<NWIN * NHEADS, 256, 0, stream>>>(qw, kw, vw, EB, use_shift, aw);
    out_proj_mfma_kernel<<<PGRID, 256, 0, stream>>>(aw, Wf + 3 * 9216, bp, use_shift, (float*)d_out);
}